// Round 4
// baseline (815.375 us; speedup 1.0000x reference)
//
#include <hip/hip_runtime.h>
#include <stdint.h>

typedef unsigned short u16;
typedef __attribute__((ext_vector_type(8))) short short8;
typedef __attribute__((ext_vector_type(8))) unsigned short ushortx8;
typedef __attribute__((ext_vector_type(4))) float floatx4;

#define DEV __device__ __forceinline__

DEV u16 f2bf(float f) {  // RNE
  union { float f; unsigned u; } x; x.f = f;
  unsigned u = x.u + 0x7fffu + ((x.u >> 16) & 1u);
  return (u16)(u >> 16);
}
DEV float bf2f(u16 h) {
  union { unsigned u; float f; } x; x.u = ((unsigned)h) << 16;
  return x.f;
}
DEV float scrub(float x) {
  return fminf(fmaxf(x, -65504.0f), 65504.0f);
}
DEV void async16(const void* g, void* l) {
  auto gp = reinterpret_cast<const __attribute__((address_space(1))) unsigned int*>(
      reinterpret_cast<uintptr_t>(g));
  auto lp = reinterpret_cast<__attribute__((address_space(3))) unsigned int*>(
      reinterpret_cast<uintptr_t>(l));
  __builtin_amdgcn_global_load_lds(gp, lp, 16, 0, 0);
}

// ===========================================================================
// fp32 -> bf16 elementwise convert (RNE), 4 elems/thread
// ===========================================================================
__global__ void cvt_bf16(const float* __restrict__ s, u16* __restrict__ d, int n4) {
  int i = blockIdx.x * 256 + threadIdx.x;
  if (i < n4) {
    float4 v = ((const float4*)s)[i];
    union { u16 h[4]; uint2 u; } o;
    o.h[0] = f2bf(v.x); o.h[1] = f2bf(v.y); o.h[2] = f2bf(v.z); o.h[3] = f2bf(v.w);
    ((uint2*)d)[i] = o.u;
  }
}

// ===========================================================================
// FAST bf16 NT GEMM (m97 structure): C[M,N] = A[M,K]*W[N,K]^T.
// global_load_lds width=16, XOR-granule LDS swizzle, 128x128 tile, BK=64.
// amode: 0 = A row-major (M x 1024) ; 1 = A head-split (B,H,L,DK)
// omode: 0 = bf16 head-split out    ; 1 = fp32 row-major out
// ===========================================================================
__global__ __launch_bounds__(256, 2) void gemm_bt(
    const u16* __restrict__ A0, const u16* __restrict__ A1, const u16* __restrict__ A2,
    const u16* __restrict__ W0, const u16* __restrict__ W1, const u16* __restrict__ W2,
    void* __restrict__ O0, void* __restrict__ O1, void* __restrict__ O2,
    int amode, int omode)
{
  constexpr int K = 1024;
  const int z = blockIdx.z;
  const u16* A = z == 0 ? A0 : (z == 1 ? A1 : A2);
  const u16* W = z == 0 ? W0 : (z == 1 ? W1 : W2);
  void* Out = z == 0 ? O0 : (z == 1 ? O1 : O2);

  const int tid = threadIdx.x;
  const int w = tid >> 6, lane = tid & 63;
  const int quad = lane >> 4, l16 = lane & 15;
  const int m0 = blockIdx.y * 128, n0 = blockIdx.x * 128;
  const int wm = (w & 1) * 64, wn = (w >> 1) * 64;

  __shared__ u16 As[128 * 64];
  __shared__ u16 Bs[128 * 64];

  floatx4 acc[4][4];
#pragma unroll
  for (int i = 0; i < 4; ++i)
#pragma unroll
    for (int j = 0; j < 4; ++j) acc[i][j] = (floatx4)0.0f;

  for (int k0 = 0; k0 < K; k0 += 64) {
#pragma unroll
    for (int i = 0; i < 4; ++i) {
      int lin = i * 256 + tid;
      int r = lin >> 3, sp = lin & 7;
      int s = sp ^ (r & 7);
      const u16* ga;
      if (amode == 1) {
        int row = m0 + r;  // head-split: k-tile == head (k0 multiple of 64)
        ga = A + (((size_t)(row >> 11) * 16 + (k0 >> 6)) * 2048 + (row & 2047)) * 64 + s * 8;
      } else {
        ga = A + (size_t)(m0 + r) * K + k0 + s * 8;
      }
      async16(ga, &As[lin * 8]);
    }
#pragma unroll
    for (int i = 0; i < 4; ++i) {
      int lin = i * 256 + tid;
      int r = lin >> 3, sp = lin & 7;
      int s = sp ^ (r & 7);
      async16(W + (size_t)(n0 + r) * K + k0 + s * 8, &Bs[lin * 8]);
    }
    asm volatile("s_waitcnt vmcnt(0)" ::: "memory");
    __syncthreads();

#pragma unroll
    for (int kk = 0; kk < 2; ++kk) {
      short8 af[4], bf[4];
#pragma unroll
      for (int mi = 0; mi < 4; ++mi) {
        int r = wm + mi * 16 + l16;
        af[mi] = *(const short8*)&As[r * 64 + (((kk * 4 + quad) ^ (r & 7)) * 8)];
      }
#pragma unroll
      for (int ni = 0; ni < 4; ++ni) {
        int r = wn + ni * 16 + l16;
        bf[ni] = *(const short8*)&Bs[r * 64 + (((kk * 4 + quad) ^ (r & 7)) * 8)];
      }
#pragma unroll
      for (int mi = 0; mi < 4; ++mi)
#pragma unroll
        for (int ni = 0; ni < 4; ++ni)
          acc[mi][ni] = __builtin_amdgcn_mfma_f32_16x16x32_bf16(af[mi], bf[ni], acc[mi][ni], 0, 0, 0);
    }
    __syncthreads();
  }

#pragma unroll
  for (int mi = 0; mi < 4; ++mi) {
#pragma unroll
    for (int ni = 0; ni < 4; ++ni) {
      int rr = m0 + wm + mi * 16 + quad * 4;
      int cc = n0 + wn + ni * 16 + l16;
#pragma unroll
      for (int reg = 0; reg < 4; ++reg) {
        int row = rr + reg;
        if (omode == 0) {
          int bb = row >> 11, ll = row & 2047;
          int hh = cc >> 6, dk = cc & 63;
          ((u16*)Out)[(((size_t)bb * 16 + hh) * 2048 + ll) * 64 + dk] = f2bf(acc[mi][ni][reg]);
        } else {
          ((float*)Out)[(size_t)row * 1024 + cc] = acc[mi][ni][reg];
        }
      }
    }
  }
}

// ===========================================================================
// SLOW-path GEMMs (round-3, proven): used only if ws_size is small.
// ===========================================================================
__global__ __launch_bounds__(256, 2) void proj_gemm(
    const float* __restrict__ Aq, const float* __restrict__ Ak, const float* __restrict__ Av,
    const float* __restrict__ Wq, const float* __restrict__ Wk, const float* __restrict__ Wv,
    u16* __restrict__ Oq, u16* __restrict__ Ok, u16* __restrict__ Ov)
{
  constexpr int K = 1024;
  const int z = blockIdx.z;
  const float* A = z == 0 ? Aq : (z == 1 ? Ak : Av);
  const float* W = z == 0 ? Wq : (z == 1 ? Wk : Wv);
  u16* Out = z == 0 ? Oq : (z == 1 ? Ok : Ov);

  const int tid = threadIdx.x;
  const int w = tid >> 6, lane = tid & 63;
  const int quad = lane >> 4, l16 = lane & 15;
  const int m0 = blockIdx.y * 128, n0 = blockIdx.x * 128;
  const int wm = (w & 1) * 64, wn = (w >> 1) * 64;

  __shared__ u16 As[128 * 72];
  __shared__ u16 Bs[128 * 72];

  floatx4 acc[4][4];
#pragma unroll
  for (int i = 0; i < 4; ++i)
#pragma unroll
    for (int j = 0; j < 4; ++j) acc[i][j] = (floatx4)0.0f;

  for (int k0 = 0; k0 < K; k0 += 64) {
#pragma unroll
    for (int i = 0; i < 8; ++i) {
      int lin = i * 256 + tid;
      int row = lin >> 4, c4 = (lin & 15) * 4;
      float4 a = *(const float4*)&A[(size_t)(m0 + row) * K + k0 + c4];
      u16* d = &As[row * 72 + c4];
      d[0] = f2bf(a.x); d[1] = f2bf(a.y); d[2] = f2bf(a.z); d[3] = f2bf(a.w);
    }
#pragma unroll
    for (int i = 0; i < 8; ++i) {
      int lin = i * 256 + tid;
      int row = lin >> 4, c4 = (lin & 15) * 4;
      float4 b = *(const float4*)&W[(size_t)(n0 + row) * K + k0 + c4];
      u16* d = &Bs[row * 72 + c4];
      d[0] = f2bf(b.x); d[1] = f2bf(b.y); d[2] = f2bf(b.z); d[3] = f2bf(b.w);
    }
    __syncthreads();

#pragma unroll
    for (int kk = 0; kk < 2; ++kk) {
      short8 af[4], bf[4];
#pragma unroll
      for (int mi = 0; mi < 4; ++mi)
        af[mi] = *(const short8*)&As[(wm + mi * 16 + l16) * 72 + kk * 32 + quad * 8];
#pragma unroll
      for (int ni = 0; ni < 4; ++ni)
        bf[ni] = *(const short8*)&Bs[(wn + ni * 16 + l16) * 72 + kk * 32 + quad * 8];
#pragma unroll
      for (int mi = 0; mi < 4; ++mi)
#pragma unroll
        for (int ni = 0; ni < 4; ++ni)
          acc[mi][ni] = __builtin_amdgcn_mfma_f32_16x16x32_bf16(af[mi], bf[ni], acc[mi][ni], 0, 0, 0);
    }
    __syncthreads();
  }

#pragma unroll
  for (int mi = 0; mi < 4; ++mi) {
#pragma unroll
    for (int ni = 0; ni < 4; ++ni) {
      int rr = m0 + wm + mi * 16 + quad * 4;
      int cc = n0 + wn + ni * 16 + l16;
#pragma unroll
      for (int reg = 0; reg < 4; ++reg) {
        int row = rr + reg;
        int bb = row >> 11, ll = row & 2047;
        int hh = cc >> 6, dk = cc & 63;
        Out[(((size_t)bb * 16 + hh) * 2048 + ll) * 64 + dk] = f2bf(scrub(acc[mi][ni][reg]));
      }
    }
  }
}

__global__ __launch_bounds__(256, 2) void out_gemm(
    const u16* __restrict__ Ah, const float* __restrict__ Wo, float* __restrict__ Out)
{
  constexpr int K = 1024;
  const int tid = threadIdx.x;
  const int w = tid >> 6, lane = tid & 63;
  const int quad = lane >> 4, l16 = lane & 15;
  const int m0 = blockIdx.y * 128, n0 = blockIdx.x * 128;
  const int wm = (w & 1) * 64, wn = (w >> 1) * 64;

  __shared__ u16 As[128 * 72];
  __shared__ u16 Bs[128 * 72];

  floatx4 acc[4][4];
#pragma unroll
  for (int i = 0; i < 4; ++i)
#pragma unroll
    for (int j = 0; j < 4; ++j) acc[i][j] = (floatx4)0.0f;

  for (int k0 = 0; k0 < K; k0 += 64) {
    int hh = k0 >> 6;
#pragma unroll
    for (int i = 0; i < 4; ++i) {
      int lin = i * 256 + tid;
      int row = lin >> 3, s = lin & 7;
      int gr = m0 + row;
      int bb = gr >> 11, tok = gr & 2047;
      ushortx8 v8 = *(const ushortx8*)&Ah[(((size_t)bb * 16 + hh) * 2048 + tok) * 64 + s * 8];
      *(ushortx8*)&As[row * 72 + s * 8] = v8;
    }
#pragma unroll
    for (int i = 0; i < 8; ++i) {
      int lin = i * 256 + tid;
      int row = lin >> 4, c4 = (lin & 15) * 4;
      float4 b = *(const float4*)&Wo[(size_t)(n0 + row) * K + k0 + c4];
      u16* d = &Bs[row * 72 + c4];
      d[0] = f2bf(b.x); d[1] = f2bf(b.y); d[2] = f2bf(b.z); d[3] = f2bf(b.w);
    }
    __syncthreads();

#pragma unroll
    for (int kk = 0; kk < 2; ++kk) {
      short8 af[4], bf[4];
#pragma unroll
      for (int mi = 0; mi < 4; ++mi)
        af[mi] = *(const short8*)&As[(wm + mi * 16 + l16) * 72 + kk * 32 + quad * 8];
#pragma unroll
      for (int ni = 0; ni < 4; ++ni)
        bf[ni] = *(const short8*)&Bs[(wn + ni * 16 + l16) * 72 + kk * 32 + quad * 8];
#pragma unroll
      for (int mi = 0; mi < 4; ++mi)
#pragma unroll
        for (int ni = 0; ni < 4; ++ni)
          acc[mi][ni] = __builtin_amdgcn_mfma_f32_16x16x32_bf16(af[mi], bf[ni], acc[mi][ni], 0, 0, 0);
    }
    __syncthreads();
  }

#pragma unroll
  for (int mi = 0; mi < 4; ++mi) {
#pragma unroll
    for (int ni = 0; ni < 4; ++ni) {
      int rr = m0 + wm + mi * 16 + quad * 4;
      int cc = n0 + wn + ni * 16 + l16;
#pragma unroll
      for (int reg = 0; reg < 4; ++reg)
        Out[(size_t)(rr + reg) * 1024 + cc] = scrub(acc[mi][ni][reg]);
    }
  }
}

// ===========================================================================
// Flash attention v2: BK=128 keys/iter, swizzled LDS (conflict-free V^T),
// 48 KB LDS -> 3 blocks/CU. Wave w owns Q rows [w*32, w*32+32).
// ===========================================================================
__global__ __launch_bounds__(256, 3) void attn2(
    const u16* Qh, const u16* __restrict__ Kh,
    const u16* __restrict__ Vh, u16* O)
{
  constexpr int L = 2048, DK = 64, H = 16;
  constexpr float SC2 = 0.125f * 1.44269504088896f;  // SCALE * log2(e)

  const int tid = threadIdx.x;
  const int w = tid >> 6, lane = tid & 63;
  const int quad = lane >> 4, l16 = lane & 15;
  const int q0 = blockIdx.x * 128, h = blockIdx.y, b = blockIdx.z;
  const int bh = b * H + h;

  __shared__ u16 QP[128 * 64];  // Q staging (swizzled); later per-wave P slices
  __shared__ u16 Ks[128 * 64];  // 128 keys x 64 dk, swizzled
  __shared__ u16 Vt[64 * 128];  // 64 dk x 128 keys, granule ^(dk>>3) swizzle

  const u16* Qg = Qh + ((size_t)bh * L + q0) * DK;
  const u16* Kb = Kh + (size_t)bh * L * DK;
  const u16* Vb = Vh + (size_t)bh * L * DK;

  // ---- stage Q (async, swizzled) ----
#pragma unroll
  for (int i = 0; i < 4; ++i) {
    int lin = i * 256 + tid;
    int r = lin >> 3, sp = lin & 7;
    int s = sp ^ (r & 7);
    async16(Qg + (size_t)r * DK + s * 8, &QP[lin * 8]);
  }
  asm volatile("s_waitcnt vmcnt(0)" ::: "memory");
  __syncthreads();

  short8 qf[2][2];
#pragma unroll
  for (int mi = 0; mi < 2; ++mi)
#pragma unroll
    for (int kk = 0; kk < 2; ++kk) {
      int r = w * 32 + mi * 16 + l16;
      qf[mi][kk] = *(const short8*)&QP[r * 64 + (((kk * 4 + quad) ^ (r & 7)) * 8)];
    }

  floatx4 o[2][4];
  float m_i[2][4], l_i[2][4];
#pragma unroll
  for (int mi = 0; mi < 2; ++mi) {
#pragma unroll
    for (int nt = 0; nt < 4; ++nt) o[mi][nt] = (floatx4)0.0f;
#pragma unroll
    for (int r = 0; r < 4; ++r) { m_i[mi][r] = -1e30f; l_i[mi][r] = 0.0f; }
  }

  u16* Pl = &QP[(w * 32) * 64];  // wave-private 32x64 slice

  for (int j0 = 0; j0 < L; j0 += 128) {
    __syncthreads();  // prior-iter frag reads done before restage
    // ---- stage K (async, swizzled) ----
#pragma unroll
    for (int i = 0; i < 4; ++i) {
      int lin = i * 256 + tid;
      int r = lin >> 3, sp = lin & 7;
      int s = sp ^ (r & 7);
      async16(Kb + (size_t)(j0 + r) * DK + s * 8, &Ks[lin * 8]);
    }
    // ---- stage V transposed: Vt[dk][key], granule (key>>3)^(dk>>3) ----
#pragma unroll
    for (int i = 0; i < 4; ++i) {
      int lin = i * 256 + tid;
      int r = lin >> 3, c8 = (lin & 7) * 8;  // r = key 0..127, c8 = dk base
      ushortx8 vv = *(const ushortx8*)&Vb[(size_t)(j0 + r) * DK + c8];
#pragma unroll
      for (int j = 0; j < 8; ++j) {
        int dk = c8 + j;
        Vt[dk * 128 + (((r >> 3) ^ (dk >> 3)) * 8) + (r & 7)] = vv[j];
      }
    }
    asm volatile("s_waitcnt vmcnt(0)" ::: "memory");
    __syncthreads();

    // ---- S = Q K^T over 128 keys ----
    floatx4 s[2][8];
#pragma unroll
    for (int mi = 0; mi < 2; ++mi)
#pragma unroll
      for (int nt = 0; nt < 8; ++nt) s[mi][nt] = (floatx4)0.0f;
#pragma unroll
    for (int nt = 0; nt < 8; ++nt) {
#pragma unroll
      for (int kk = 0; kk < 2; ++kk) {
        int kr = nt * 16 + l16;
        short8 kf = *(const short8*)&Ks[kr * 64 + (((kk * 4 + quad) ^ (kr & 7)) * 8)];
#pragma unroll
        for (int mi = 0; mi < 2; ++mi)
          s[mi][nt] = __builtin_amdgcn_mfma_f32_16x16x32_bf16(qf[mi][kk], kf, s[mi][nt], 0, 0, 0);
      }
    }

    // ---- online softmax over the 128-key tile ----
#pragma unroll
    for (int mi = 0; mi < 2; ++mi) {
#pragma unroll
      for (int nt = 0; nt < 8; ++nt) s[mi][nt] *= SC2;
      float mx[4], al[4], rs[4];
#pragma unroll
      for (int r = 0; r < 4; ++r) {
        float m01 = fmaxf(s[mi][0][r], s[mi][1][r]);
        float m23 = fmaxf(s[mi][2][r], s[mi][3][r]);
        float m45 = fmaxf(s[mi][4][r], s[mi][5][r]);
        float m67 = fmaxf(s[mi][6][r], s[mi][7][r]);
        mx[r] = fmaxf(fmaxf(m01, m23), fmaxf(m45, m67));
      }
#pragma unroll
      for (int off = 1; off < 16; off <<= 1)
#pragma unroll
        for (int r = 0; r < 4; ++r)
          mx[r] = fmaxf(mx[r], __shfl_xor(mx[r], off, 16));
#pragma unroll
      for (int r = 0; r < 4; ++r) {
        float mnew = fmaxf(m_i[mi][r], mx[r]);
        al[r] = exp2f(fminf(m_i[mi][r] - mnew, 0.0f));
        m_i[mi][r] = mnew;
        float acc = 0.0f;
#pragma unroll
        for (int nt = 0; nt < 8; ++nt) {
          float p = exp2f(fminf(s[mi][nt][r] - mnew, 0.0f));
          float pt = __uint_as_float(__float_as_uint(p) & 0xffff0000u);  // trunc-bf16
          s[mi][nt][r] = pt;   // store P in-place
          acc += pt;           // l consistent with stored P
        }
        rs[r] = acc;
      }
#pragma unroll
      for (int off = 1; off < 16; off <<= 1)
#pragma unroll
        for (int r = 0; r < 4; ++r)
          rs[r] += __shfl_xor(rs[r], off, 16);
#pragma unroll
      for (int r = 0; r < 4; ++r) {
        l_i[mi][r] = l_i[mi][r] * al[r] + rs[r];
#pragma unroll
        for (int nt = 0; nt < 4; ++nt) o[mi][nt][r] *= al[r];
      }
    }

    // ---- O += P V in two 64-key halves (wave-private Pl reuse) ----
#pragma unroll
    for (int kh = 0; kh < 2; ++kh) {
#pragma unroll
      for (int mi = 0; mi < 2; ++mi)
#pragma unroll
        for (int nti = 0; nti < 4; ++nti)
#pragma unroll
          for (int r = 0; r < 4; ++r) {
            int row = mi * 16 + quad * 4 + r;
            int col = nti * 16 + l16;
            Pl[row * 64 + ((((col >> 3) ^ (row & 7)) * 8) + (col & 7))] =
                (u16)(__float_as_uint(s[mi][kh * 4 + nti][r]) >> 16);
          }
      asm volatile("s_waitcnt lgkmcnt(0)" ::: "memory");
      short8 pf[2][2], vf[4][2];
#pragma unroll
      for (int mi = 0; mi < 2; ++mi)
#pragma unroll
        for (int k2 = 0; k2 < 2; ++k2) {
          int row = mi * 16 + l16;
          pf[mi][k2] = *(const short8*)&Pl[row * 64 + (((k2 * 4 + quad) ^ (row & 7)) * 8)];
        }
#pragma unroll
      for (int nd = 0; nd < 4; ++nd)
#pragma unroll
        for (int k2 = 0; k2 < 2; ++k2) {
          int dk = nd * 16 + l16;
          vf[nd][k2] = *(const short8*)&Vt[dk * 128 + (((kh * 8 + k2 * 4 + quad) ^ (dk >> 3)) * 8)];
        }
#pragma unroll
      for (int mi = 0; mi < 2; ++mi)
#pragma unroll
        for (int nd = 0; nd < 4; ++nd)
#pragma unroll
          for (int k2 = 0; k2 < 2; ++k2)
            o[mi][nd] = __builtin_amdgcn_mfma_f32_16x16x32_bf16(pf[mi][k2], vf[nd][k2], o[mi][nd], 0, 0, 0);
    }
  }

  // ---- epilogue: write O over this block's own head-split Q rows ----
#pragma unroll
  for (int mi = 0; mi < 2; ++mi) {
    float inv[4];
#pragma unroll
    for (int r = 0; r < 4; ++r) inv[r] = 1.0f / fmaxf(l_i[mi][r], 1e-30f);
#pragma unroll
    for (int nt = 0; nt < 4; ++nt)
#pragma unroll
      for (int r = 0; r < 4; ++r) {
        int token = q0 + w * 32 + mi * 16 + quad * 4 + r;
        O[((size_t)bh * L + token) * 64 + nt * 16 + l16] =
            f2bf(scrub(o[mi][nt][r] * inv[r]));
      }
  }
}

// ===========================================================================
extern "C" void kernel_launch(void* const* d_in, const int* in_sizes, int n_in,
                              void* d_out, int out_size, void* d_ws, size_t ws_size,
                              hipStream_t stream) {
  const float* q  = (const float*)d_in[0];
  const float* k  = (const float*)d_in[1];
  const float* v  = (const float*)d_in[2];
  const float* wq = (const float*)d_in[3];
  const float* wk = (const float*)d_in[4];
  const float* wv = (const float*)d_in[5];
  const float* wo = (const float*)d_in[6];
  float* out = (float*)d_out;

  const size_t NE = (size_t)4 * 16 * 2048 * 64;  // 8388608
  const size_t WN = (size_t)1024 * 1024;         // 1048576
  // K,V head-split scratch live in d_out (32 MiB fp32), dead before the
  // final fp32 overwrite (stream-ordered) — proven in round 3.
  u16* Kh = (u16*)d_out;
  u16* Vh = Kh + NE;

  const size_t need_fast = (4 * NE + 4 * WN) * sizeof(u16);  // 72 MiB

  if (ws_size >= need_fast) {
    // ---- FAST path: pre-convert to bf16, async-staged GEMMs ----
    u16* qb  = (u16*)d_ws;
    u16* kb  = qb + NE;
    u16* vb  = kb + NE;
    u16* wqb = vb + NE;
    u16* wkb = wqb + WN;
    u16* wvb = wkb + WN;
    u16* wob = wvb + WN;
    u16* Qh  = wob + WN;

    int n4a = (int)(NE / 4), n4w = (int)(WN / 4);
    cvt_bf16<<<(n4a + 255) / 256, 256, 0, stream>>>(q,  qb,  n4a);
    cvt_bf16<<<(n4a + 255) / 256, 256, 0, stream>>>(k,  kb,  n4a);
    cvt_bf16<<<(n4a + 255) / 256, 256, 0, stream>>>(v,  vb,  n4a);
    cvt_bf16<<<(n4w + 255) / 256, 256, 0, stream>>>(wq, wqb, n4w);
    cvt_bf16<<<(n4w + 255) / 256, 256, 0, stream>>>(wk, wkb, n4w);
    cvt_bf16<<<(n4w + 255) / 256, 256, 0, stream>>>(wv, wvb, n4w);
    cvt_bf16<<<(n4w + 255) / 256, 256, 0, stream>>>(wo, wob, n4w);

    dim3 g1(8, 64, 3);
    gemm_bt<<<g1, dim3(256), 0, stream>>>(qb, kb, vb, wqb, wkb, wvb,
                                          Qh, Kh, Vh, 0, 0);
    dim3 g2(16, 16, 4);
    attn2<<<g2, dim3(256), 0, stream>>>(Qh, Kh, Vh, Qh);

    dim3 g3(8, 64, 1);
    gemm_bt<<<g3, dim3(256), 0, stream>>>(Qh, Qh, Qh, wob, wob, wob,
                                          out, out, out, 1, 1);
  } else {
    // ---- fallback (round-3 proven): fp32-staging GEMMs ----
    u16* Qh = (u16*)d_ws;  // 16 MiB
    dim3 g1(8, 64, 3);
    proj_gemm<<<g1, dim3(256), 0, stream>>>(q, k, v, wq, wk, wv, Qh, Kh, Vh);
    dim3 g2(16, 16, 4);
    attn2<<<g2, dim3(256), 0, stream>>>(Qh, Kh, Vh, Qh);
    dim3 g3(8, 64, 1);
    out_gemm<<<g3, dim3(256), 0, stream>>>(Qh, wo, out);
  }
}

// Round 6
// 398.704 us; speedup vs baseline: 2.0451x; 2.0451x over previous
//
#include <hip/hip_runtime.h>
#include <stdint.h>

typedef unsigned short u16;
typedef __attribute__((ext_vector_type(8))) short short8;
typedef __attribute__((ext_vector_type(4))) float floatx4;

#define DEV __device__ __forceinline__

DEV u16 f2bf(float f) {  // RNE
  union { float f; unsigned u; } x; x.f = f;
  unsigned u = x.u + 0x7fffu + ((x.u >> 16) & 1u);
  return (u16)(u >> 16);
}
DEV float scrub(float x) {
  return fminf(fmaxf(x, -65504.0f), 65504.0f);
}
DEV void async16(const void* g, void* l) {
  auto gp = reinterpret_cast<const __attribute__((address_space(1))) unsigned int*>(
      reinterpret_cast<uintptr_t>(g));
  auto lp = reinterpret_cast<__attribute__((address_space(3))) unsigned int*>(
      reinterpret_cast<uintptr_t>(l));
  __builtin_amdgcn_global_load_lds(gp, lp, 16, 0, 0);
}
DEV unsigned asu(float f) { union { float f; unsigned u; } x; x.f = f; return x.u; }
DEV float asf(unsigned u) { union { unsigned u; float f; } x; x.u = u; return x.f; }

// ===========================================================================
// fp32 -> bf16 elementwise convert (RNE), 4 elems/thread
// ===========================================================================
__global__ void cvt_bf16(const float* __restrict__ s, u16* __restrict__ d, int n4) {
  int i = blockIdx.x * 256 + threadIdx.x;
  if (i < n4) {
    float4 v = ((const float4*)s)[i];
    union { u16 h[4]; uint2 u; } o;
    o.h[0] = f2bf(v.x); o.h[1] = f2bf(v.y); o.h[2] = f2bf(v.z); o.h[3] = f2bf(v.w);
    ((uint2*)d)[i] = o.u;
  }
}

// ===========================================================================
// Projection GEMM (bf16 NT, m97 structure, 128x128 tile, BK=64).
// z=0 (Q): C^T orient (A=W, B=X), out head-split (B,H,L,DK), PRESCALED by
//          SCALE*log2e so attention's QK^T lands in exp2 domain.
// z=1 (K): C^T orient, head-split.
// z=2 (V): C orient (A=X, B=W), out TRANSPOSED head-split (B,H,DK,L).
// All epilogue stores are packed 8 B (4 bf16).
// ===========================================================================
__global__ __launch_bounds__(256, 2) void proj3(
    const u16* __restrict__ Xq, const u16* __restrict__ Xk, const u16* __restrict__ Xv,
    const u16* __restrict__ Wq, const u16* __restrict__ Wk, const u16* __restrict__ Wv,
    u16* __restrict__ Oq, u16* __restrict__ Ok, u16* __restrict__ Ov)
{
  constexpr int K = 1024;
  constexpr float SC2 = 0.125f * 1.44269504088896f;
  const int z = blockIdx.z;
  const u16* X = z == 0 ? Xq : (z == 1 ? Xk : Xv);
  const u16* W = z == 0 ? Wq : (z == 1 ? Wk : Wv);
  u16* Out = z == 0 ? Oq : (z == 1 ? Ok : Ov);

  const u16* A = (z < 2) ? W : X;
  const u16* Bp = (z < 2) ? X : W;
  const int m0 = (z < 2) ? blockIdx.x * 128 : blockIdx.y * 128;
  const int n0 = (z < 2) ? blockIdx.y * 128 : blockIdx.x * 128;

  const int tid = threadIdx.x;
  const int w = tid >> 6, lane = tid & 63;
  const int quad = lane >> 4, l16 = lane & 15;
  const int wm = (w & 1) * 64, wn = (w >> 1) * 64;

  __shared__ u16 As[128 * 64];
  __shared__ u16 Bs[128 * 64];

  floatx4 acc[4][4];
#pragma unroll
  for (int i = 0; i < 4; ++i)
#pragma unroll
    for (int j = 0; j < 4; ++j) acc[i][j] = (floatx4)0.0f;

  for (int k0 = 0; k0 < K; k0 += 64) {
#pragma unroll
    for (int i = 0; i < 4; ++i) {
      int lin = i * 256 + tid;
      int r = lin >> 3, sp = lin & 7, s = sp ^ (r & 7);
      async16(A + (size_t)(m0 + r) * K + k0 + s * 8, &As[lin * 8]);
    }
#pragma unroll
    for (int i = 0; i < 4; ++i) {
      int lin = i * 256 + tid;
      int r = lin >> 3, sp = lin & 7, s = sp ^ (r & 7);
      async16(Bp + (size_t)(n0 + r) * K + k0 + s * 8, &Bs[lin * 8]);
    }
    asm volatile("s_waitcnt vmcnt(0)" ::: "memory");
    __syncthreads();

#pragma unroll
    for (int kk = 0; kk < 2; ++kk) {
      short8 af[4], bf[4];
#pragma unroll
      for (int mi = 0; mi < 4; ++mi) {
        int r = wm + mi * 16 + l16;
        af[mi] = *(const short8*)&As[r * 64 + (((kk * 4 + quad) ^ (r & 7)) * 8)];
      }
#pragma unroll
      for (int ni = 0; ni < 4; ++ni) {
        int r = wn + ni * 16 + l16;
        bf[ni] = *(const short8*)&Bs[r * 64 + (((kk * 4 + quad) ^ (r & 7)) * 8)];
      }
#pragma unroll
      for (int mi = 0; mi < 4; ++mi)
#pragma unroll
        for (int ni = 0; ni < 4; ++ni)
          acc[mi][ni] = __builtin_amdgcn_mfma_f32_16x16x32_bf16(af[mi], bf[ni], acc[mi][ni], 0, 0, 0);
    }
    __syncthreads();
  }

  const float sc = (z == 0) ? SC2 : 1.0f;
#pragma unroll
  for (int mi = 0; mi < 4; ++mi) {
#pragma unroll
    for (int ni = 0; ni < 4; ++ni) {
      int rr = m0 + wm + mi * 16 + quad * 4;
      int cc = n0 + wn + ni * 16 + l16;
      u16 h0 = f2bf(sc * acc[mi][ni][0]);
      u16 h1 = f2bf(sc * acc[mi][ni][1]);
      u16 h2 = f2bf(sc * acc[mi][ni][2]);
      u16 h3 = f2bf(sc * acc[mi][ni][3]);
      uint2 dw; dw.x = h0 | ((unsigned)h1 << 16); dw.y = h2 | ((unsigned)h3 << 16);
      if (z < 2) {
        int bb = cc >> 11, ll = cc & 2047;
        int hh = rr >> 6, dk0 = rr & 63;
        *(uint2*)&Out[(((size_t)bb * 16 + hh) * 2048 + ll) * 64 + dk0] = dw;
      } else {
        int bb = rr >> 11, ll0 = rr & 2047;
        int hh = cc >> 6, dk = cc & 63;
        *(uint2*)&Out[(((size_t)bb * 16 + hh) * 64 + dk) * 2048 + ll0] = dw;
      }
    }
  }
}

// ===========================================================================
// Output GEMM: C[M,N] = A[M,K]*W[N,K]^T. A bf16 head-split, W bf16,
// C fp32 row-major (final output).
// ===========================================================================
__global__ __launch_bounds__(256, 2) void gemm_out(
    const u16* __restrict__ Ah, const u16* __restrict__ Wo, float* __restrict__ Out)
{
  constexpr int K = 1024;
  const int tid = threadIdx.x;
  const int w = tid >> 6, lane = tid & 63;
  const int quad = lane >> 4, l16 = lane & 15;
  const int m0 = blockIdx.y * 128, n0 = blockIdx.x * 128;
  const int wm = (w & 1) * 64, wn = (w >> 1) * 64;

  __shared__ u16 As[128 * 64];
  __shared__ u16 Bs[128 * 64];

  floatx4 acc[4][4];
#pragma unroll
  for (int i = 0; i < 4; ++i)
#pragma unroll
    for (int j = 0; j < 4; ++j) acc[i][j] = (floatx4)0.0f;

  for (int k0 = 0; k0 < K; k0 += 64) {
#pragma unroll
    for (int i = 0; i < 4; ++i) {
      int lin = i * 256 + tid;
      int r = lin >> 3, sp = lin & 7, s = sp ^ (r & 7);
      int row = m0 + r;  // head-split A: k-tile == head
      const u16* ga = Ah + (((size_t)(row >> 11) * 16 + (k0 >> 6)) * 2048 + (row & 2047)) * 64 + s * 8;
      async16(ga, &As[lin * 8]);
    }
#pragma unroll
    for (int i = 0; i < 4; ++i) {
      int lin = i * 256 + tid;
      int r = lin >> 3, sp = lin & 7, s = sp ^ (r & 7);
      async16(Wo + (size_t)(n0 + r) * K + k0 + s * 8, &Bs[lin * 8]);
    }
    asm volatile("s_waitcnt vmcnt(0)" ::: "memory");
    __syncthreads();

#pragma unroll
    for (int kk = 0; kk < 2; ++kk) {
      short8 af[4], bf[4];
#pragma unroll
      for (int mi = 0; mi < 4; ++mi) {
        int r = wm + mi * 16 + l16;
        af[mi] = *(const short8*)&As[r * 64 + (((kk * 4 + quad) ^ (r & 7)) * 8)];
      }
#pragma unroll
      for (int ni = 0; ni < 4; ++ni) {
        int r = wn + ni * 16 + l16;
        bf[ni] = *(const short8*)&Bs[r * 64 + (((kk * 4 + quad) ^ (r & 7)) * 8)];
      }
#pragma unroll
      for (int mi = 0; mi < 4; ++mi)
#pragma unroll
        for (int ni = 0; ni < 4; ++ni)
          acc[mi][ni] = __builtin_amdgcn_mfma_f32_16x16x32_bf16(af[mi], bf[ni], acc[mi][ni], 0, 0, 0);
    }
    __syncthreads();
  }

#pragma unroll
  for (int mi = 0; mi < 4; ++mi)
#pragma unroll
    for (int ni = 0; ni < 4; ++ni) {
      int rr = m0 + wm + mi * 16 + quad * 4;
      int cc = n0 + wn + ni * 16 + l16;
#pragma unroll
      for (int reg = 0; reg < 4; ++reg)
        Out[(size_t)(rr + reg) * 1024 + cc] = scrub(acc[mi][ni][reg]);
    }
}

// ===========================================================================
// Flash attention v3b (S^T / O^T): grid (L/128, H, B), 256 threads.
// Q prescaled by SCALE*log2e at projection. V supplied TRANSPOSED (B,H,DK,L).
// S^T = K*Q^T (per-lane q column -> scalar m/l, 2-shfl reductions).
// P^T B-frag by DIRECT register packing under a relabeled contraction order
// (slot quad*8+j: j<4 -> tile 2kk row quad*4+j; j>=4 -> tile 2kk+1 row
// quad*4+j-4). V^T A-frag reads the SAME key order as two 8B LDS chunks.
// No cross-lane ops, no LDS round-trip for P. Double-buffered K/V tiles.
// ===========================================================================
__global__ __launch_bounds__(256, 2) void attn3(
    const u16* Qh, const u16* __restrict__ Kh,
    const u16* __restrict__ VT, u16* O)
{
  constexpr int L = 2048, DK = 64, H = 16;
  const int tid = threadIdx.x;
  const int w = tid >> 6, lane = tid & 63;
  const int quad = lane >> 4, l16 = lane & 15;
  const int q0 = blockIdx.x * 128, h = blockIdx.y, b = blockIdx.z;
  const int bh = b * H + h;

  __shared__ u16 QP[128 * 64];
  __shared__ u16 Ks[2][64 * 64];
  __shared__ u16 Vt[2][64 * 64];

  const u16* Qg = Qh + ((size_t)bh * L + q0) * DK;
  const u16* Kb = Kh + (size_t)bh * L * DK;
  const u16* Vb = VT + (size_t)bh * DK * L;  // rows = dk, length L

#pragma unroll
  for (int i = 0; i < 4; ++i) {
    int lin = i * 256 + tid;
    int r = lin >> 3, sp = lin & 7, s = sp ^ (r & 7);
    async16(Qg + (size_t)r * DK + s * 8, &QP[lin * 8]);
  }

  auto stage = [&](int p, int j0) {
#pragma unroll
    for (int i = 0; i < 2; ++i) {
      int lin = i * 256 + tid;
      int r = lin >> 3, sp = lin & 7, s = sp ^ (r & 7);
      async16(Kb + (size_t)(j0 + r) * DK + s * 8, &Ks[p][lin * 8]);
    }
#pragma unroll
    for (int i = 0; i < 2; ++i) {
      int lin = i * 256 + tid;
      int r = lin >> 3, sp = lin & 7, s = sp ^ (r & 7);
      async16(Vb + (size_t)r * L + j0 + s * 8, &Vt[p][lin * 8]);
    }
  };

  stage(0, 0);
  asm volatile("s_waitcnt vmcnt(0)" ::: "memory");
  __syncthreads();

  short8 qf[2][2];
#pragma unroll
  for (int mi = 0; mi < 2; ++mi)
#pragma unroll
    for (int kk = 0; kk < 2; ++kk) {
      int r = w * 32 + mi * 16 + l16;
      qf[mi][kk] = *(const short8*)&QP[r * 64 + (((kk * 4 + quad) ^ (r & 7)) * 8)];
    }

  floatx4 oT[4][2];   // [dk-tile][q-tile]
  float m_i[2], l_i[2];
#pragma unroll
  for (int nd = 0; nd < 4; ++nd)
#pragma unroll
    for (int mi = 0; mi < 2; ++mi) oT[nd][mi] = (floatx4)0.0f;
  m_i[0] = m_i[1] = -1e30f;
  l_i[0] = l_i[1] = 0.0f;

  int p = 0;
  for (int j0 = 0; j0 < L; j0 += 64, p ^= 1) {
    if (j0 + 64 < L) stage(p ^ 1, j0 + 64);

    // ---- S^T = K Q^T : lane holds keys kt*16+quad*4+r at col q=l16 ----
    floatx4 sT[4][2];
#pragma unroll
    for (int kt = 0; kt < 4; ++kt)
#pragma unroll
      for (int mi = 0; mi < 2; ++mi) sT[kt][mi] = (floatx4)0.0f;
#pragma unroll
    for (int kt = 0; kt < 4; ++kt)
#pragma unroll
      for (int kk = 0; kk < 2; ++kk) {
        int r = kt * 16 + l16;
        short8 kf = *(const short8*)&Ks[p][r * 64 + (((kk * 4 + quad) ^ (r & 7)) * 8)];
#pragma unroll
        for (int mi = 0; mi < 2; ++mi)
          sT[kt][mi] = __builtin_amdgcn_mfma_f32_16x16x32_bf16(kf, qf[mi][kk], sT[kt][mi], 0, 0, 0);
      }

    // ---- online softmax: per-lane scalar m/l per q-column ----
    int pk[2][4][2];
#pragma unroll
    for (int mi = 0; mi < 2; ++mi) {
      float mx = -1e30f;
#pragma unroll
      for (int kt = 0; kt < 4; ++kt)
#pragma unroll
        for (int r = 0; r < 4; ++r) mx = fmaxf(mx, sT[kt][mi][r]);
      mx = fmaxf(mx, __shfl_xor(mx, 16));
      mx = fmaxf(mx, __shfl_xor(mx, 32));
      float mnew = fmaxf(m_i[mi], mx);
      float al = exp2f(m_i[mi] - mnew);
      m_i[mi] = mnew;
      float rs = 0.0f;
#pragma unroll
      for (int kt = 0; kt < 4; ++kt) {
#pragma unroll
        for (int r = 0; r < 4; ++r) {
          float pv = exp2f(sT[kt][mi][r] - mnew);
          unsigned tu = asu(pv) & 0xffff0000u;   // trunc-bf16, consistent sum
          rs += asf(tu);
          sT[kt][mi][r] = asf(tu);
        }
        pk[mi][kt][0] = (int)((asu(sT[kt][mi][0]) >> 16) | (asu(sT[kt][mi][1]) & 0xffff0000u));
        pk[mi][kt][1] = (int)((asu(sT[kt][mi][2]) >> 16) | (asu(sT[kt][mi][3]) & 0xffff0000u));
      }
      rs += __shfl_xor(rs, 16);
      rs += __shfl_xor(rs, 32);
      l_i[mi] = l_i[mi] * al + rs;
#pragma unroll
      for (int nd = 0; nd < 4; ++nd)
#pragma unroll
        for (int r = 0; r < 4; ++r) oT[nd][mi][r] *= al;
    }

    // ---- O^T += V^T P^T : direct packing under relabeled key order ----
#pragma unroll
    for (int kk = 0; kk < 2; ++kk) {
      short8 pf[2];
#pragma unroll
      for (int mi = 0; mi < 2; ++mi) {
        union { int i[4]; short8 v; } u;
        u.i[0] = pk[mi][2 * kk][0];      // slots quad*8+0,1 = tile 2kk rows quad*4+0,1
        u.i[1] = pk[mi][2 * kk][1];      // slots +2,+3
        u.i[2] = pk[mi][2 * kk + 1][0];  // slots +4,+5 = tile 2kk+1 rows quad*4+0,1
        u.i[3] = pk[mi][2 * kk + 1][1];  // slots +6,+7
        pf[mi] = u.v;
      }
#pragma unroll
      for (int nd = 0; nd < 4; ++nd) {
        int dk = nd * 16 + l16;
        int lgA = kk * 4 + (quad >> 1);           // logical granule, tile 2kk
        int pgA = lgA ^ (dk & 7);
        int pgB = (lgA + 2) ^ (dk & 7);           // tile 2kk+1
        int off = (quad & 1) * 4;                 // u16 within granule
        union { uint2 ab[2]; short8 v; } uv;
        uv.ab[0] = *(const uint2*)&Vt[p][dk * 64 + pgA * 8 + off];
        uv.ab[1] = *(const uint2*)&Vt[p][dk * 64 + pgB * 8 + off];
#pragma unroll
        for (int mi = 0; mi < 2; ++mi)
          oT[nd][mi] = __builtin_amdgcn_mfma_f32_16x16x32_bf16(uv.v, pf[mi], oT[nd][mi], 0, 0, 0);
      }
    }

    asm volatile("s_waitcnt vmcnt(0)" ::: "memory");
    __syncthreads();
  }

  // ---- epilogue: O^T lane holds dk=nd*16+quad*4+r at token col l16 ----
#pragma unroll
  for (int mi = 0; mi < 2; ++mi) {
    float inv = 1.0f / fmaxf(l_i[mi], 1e-30f);
    int token = q0 + w * 32 + mi * 16 + l16;
#pragma unroll
    for (int nd = 0; nd < 4; ++nd) {
      u16 h0 = f2bf(scrub(oT[nd][mi][0] * inv));
      u16 h1 = f2bf(scrub(oT[nd][mi][1] * inv));
      u16 h2 = f2bf(scrub(oT[nd][mi][2] * inv));
      u16 h3 = f2bf(scrub(oT[nd][mi][3] * inv));
      uint2 dw; dw.x = h0 | ((unsigned)h1 << 16); dw.y = h2 | ((unsigned)h3 << 16);
      *(uint2*)&O[((size_t)bh * L + token) * 64 + nd * 16 + quad * 4] = dw;
    }
  }
}

// ===========================================================================
extern "C" void kernel_launch(void* const* d_in, const int* in_sizes, int n_in,
                              void* d_out, int out_size, void* d_ws, size_t ws_size,
                              hipStream_t stream) {
  const float* q  = (const float*)d_in[0];
  const float* k  = (const float*)d_in[1];
  const float* v  = (const float*)d_in[2];
  const float* wq = (const float*)d_in[3];
  const float* wk = (const float*)d_in[4];
  const float* wv = (const float*)d_in[5];
  const float* wo = (const float*)d_in[6];
  float* out = (float*)d_out;

  const size_t NE = (size_t)4 * 16 * 2048 * 64;  // 8388608
  const size_t WN = (size_t)1024 * 1024;

  u16* qb  = (u16*)d_ws;
  u16* kb  = qb + NE;
  u16* vb  = kb + NE;
  u16* wqb = vb + NE;
  u16* wkb = wqb + WN;
  u16* wvb = wkb + WN;
  u16* wob = wvb + WN;
  u16* Qh  = wob + WN;          // Q head-split (prescaled); attn overwrites it
  u16* Kh  = (u16*)d_out;       // K head-split in d_out (dead before final)
  u16* VTg = Kh + NE;           // V^T (B,H,DK,L)

  int n4a = (int)(NE / 4), n4w = (int)(WN / 4);
  cvt_bf16<<<(n4a + 255) / 256, 256, 0, stream>>>(q,  qb,  n4a);
  cvt_bf16<<<(n4a + 255) / 256, 256, 0, stream>>>(k,  kb,  n4a);
  cvt_bf16<<<(n4a + 255) / 256, 256, 0, stream>>>(v,  vb,  n4a);
  cvt_bf16<<<(n4w + 255) / 256, 256, 0, stream>>>(wq, wqb, n4w);
  cvt_bf16<<<(n4w + 255) / 256, 256, 0, stream>>>(wk, wkb, n4w);
  cvt_bf16<<<(n4w + 255) / 256, 256, 0, stream>>>(wv, wvb, n4w);
  cvt_bf16<<<(n4w + 255) / 256, 256, 0, stream>>>(wo, wob, n4w);

  dim3 g1(8, 64, 3);
  proj3<<<g1, dim3(256), 0, stream>>>(qb, kb, vb, wqb, wkb, wvb, Qh, Kh, VTg);

  dim3 g2(16, 16, 4);
  attn3<<<g2, dim3(256), 0, stream>>>(Qh, Kh, VTg, Qh);

  dim3 g3(8, 64, 1);
  gemm_out<<<g3, dim3(256), 0, stream>>>(Qh, wob, out);
}